// Round 5
// baseline (13985.771 us; speedup 1.0000x reference)
//
#include <hip/hip_runtime.h>
#include <cstdint>
#include <cstddef>

// ---------------- types / helpers ----------------
typedef __attribute__((ext_vector_type(8))) short bf16x8;   // 8 bf16 in 4 VGPRs
typedef __attribute__((ext_vector_type(4))) float f32x4;
typedef __attribute__((ext_vector_type(4))) float float4v;
typedef __attribute__((ext_vector_type(4))) unsigned short ushort4v;
typedef unsigned short u16;
typedef unsigned int u32;
typedef unsigned long long u64;

#define DEVFN static __device__ __forceinline__

DEVFN u16 f2bf(float f) {               // fp32 -> bf16 round-to-nearest-even
  u32 u = __float_as_uint(f);
  return (u16)((u + 0x7fffu + ((u >> 16) & 1u)) >> 16);
}
DEVFN float bf2f(u16 h) { return __uint_as_float(((u32)h) << 16); }
DEVFN float sigmf(float x) { return 1.f / (1.f + __expf(-x)); }
DEVFN float tanhf_fast(float x) {
  float e = __expf(-2.f * fabsf(x));
  float t = (1.f - e) / (1.f + e);
  return x >= 0.f ? t : -t;
}

// dims: L=8 N=64 T=128 D=1024 H=1024 ; TL = 1024 steps ; 3H = 3072
// ws: [0,4096) barrier counters (4 groups x 256B)
//     [4096,+256KB) h bf16 [4 grp][2 buf][16 rows][1024]
static constexpr size_t WS_BAR  = 0;
static constexpr size_t WS_HBUF = 4096;
static constexpr size_t WS_WIH  = WS_HBUF + 262144;
static constexpr size_t WS_WHH  = WS_WIH + 6291456;
static constexpr size_t WS_GI   = WS_WHH + 6291456;
static constexpr size_t WS_END  = WS_GI + (size_t)65536 * 3072 * 2;  // ~396 MiB

// ---------------- fp32 -> bf16 convert ----------------
__global__ void cvt4_kernel(const float* __restrict__ src, u16* __restrict__ dst, int n4) {
  int i = blockIdx.x * blockDim.x + threadIdx.x;
  if (i >= n4) return;
  float4v v = ((const float4v*)src)[i];
  ushort4v o;
  o[0] = f2bf(v[0]); o[1] = f2bf(v[1]); o[2] = f2bf(v[2]); o[3] = f2bf(v[3]);
  ((ushort4v*)dst)[i] = o;
}

// h0 -> hbuf[grp][buf0][row][1024], grp = n>>4, row = n&15
__global__ void h0_init_kernel(const float* __restrict__ h0, u16* __restrict__ hbuf) {
  int n = blockIdx.x;                       // batch row 0..63
  const float* src = h0 + (size_t)n * 1024;
  u16* dst = hbuf + (size_t)(n >> 4) * 32768 + (size_t)(n & 15) * 1024;
  for (int i = threadIdx.x; i < 1024; i += 256) dst[i] = f2bf(src[i]);
}

// ---------------- phase A: gi = xs @ W_ih^T (bf16 out) — unchanged, proven ----------------
__launch_bounds__(256, 2)
__global__ void gemm_gi_kernel(const float* __restrict__ x, const u16* __restrict__ wih,
                               u16* __restrict__ gi) {
  const int tid = threadIdx.x;
  const int lane = tid & 63;
  const int wv = tid >> 6;
  const int bid = blockIdx.x;
  const int gt = bid % 24;
  const int rt = bid / 24;

  __shared__ __align__(16) u16 Ash[128 * 32];
  __shared__ __align__(16) u16 Bsh[128 * 32];

  const int ra = tid >> 1;
  const int ch = (tid & 1) * 16;
  const int r  = rt * 128 + ra;
  const int tp = r >> 6, n = r & 63;
  const int ll = tp & 7, tt = tp >> 3;
  const float* arow = x + ((size_t)((ll * 64 + n) * 128 + tt)) * 1024 + ch;
  const u16*   brow = wih + ((size_t)(gt * 128 + ra)) * 1024 + ch;
  const int wbyte0 = ra * 64 + ch * 2;
  const int wswz   = (ra & 7) << 4;

  const int rw = (wv >> 1) * 64;
  const int cw = (wv & 1) * 64;
  const int kb = (lane >> 4) * 16;

  f32x4 acc[4][4];
#pragma unroll
  for (int i = 0; i < 4; ++i)
#pragma unroll
    for (int j = 0; j < 4; ++j) acc[i][j] = (f32x4){0.f, 0.f, 0.f, 0.f};

  for (int kt = 0; kt < 32; ++kt) {
    float4v a0 = *(const float4v*)(arow + kt * 32 + 0);
    float4v a1 = *(const float4v*)(arow + kt * 32 + 4);
    float4v a2 = *(const float4v*)(arow + kt * 32 + 8);
    float4v a3 = *(const float4v*)(arow + kt * 32 + 12);
    bf16x8 b0 = *(const bf16x8*)(brow + kt * 32 + 0);
    bf16x8 b1 = *(const bf16x8*)(brow + kt * 32 + 8);
    union { u16 u[8]; bf16x8 v; } p0, p1;
    p0.u[0] = f2bf(a0[0]); p0.u[1] = f2bf(a0[1]); p0.u[2] = f2bf(a0[2]); p0.u[3] = f2bf(a0[3]);
    p0.u[4] = f2bf(a1[0]); p0.u[5] = f2bf(a1[1]); p0.u[6] = f2bf(a1[2]); p0.u[7] = f2bf(a1[3]);
    p1.u[0] = f2bf(a2[0]); p1.u[1] = f2bf(a2[1]); p1.u[2] = f2bf(a2[2]); p1.u[3] = f2bf(a2[3]);
    p1.u[4] = f2bf(a3[0]); p1.u[5] = f2bf(a3[1]); p1.u[6] = f2bf(a3[2]); p1.u[7] = f2bf(a3[3]);
    *(bf16x8*)((char*)Ash + ((wbyte0 +  0) ^ wswz)) = p0.v;
    *(bf16x8*)((char*)Ash + ((wbyte0 + 16) ^ wswz)) = p1.v;
    *(bf16x8*)((char*)Bsh + ((wbyte0 +  0) ^ wswz)) = b0;
    *(bf16x8*)((char*)Bsh + ((wbyte0 + 16) ^ wswz)) = b1;
    __syncthreads();

    bf16x8 af[4], bfr[4];
#pragma unroll
    for (int mi = 0; mi < 4; ++mi) {
      int row = rw + mi * 16 + (lane & 15);
      af[mi] = *(const bf16x8*)((char*)Ash + ((row * 64 + kb) ^ ((row & 7) << 4)));
    }
#pragma unroll
    for (int nj = 0; nj < 4; ++nj) {
      int row = cw + nj * 16 + (lane & 15);
      bfr[nj] = *(const bf16x8*)((char*)Bsh + ((row * 64 + kb) ^ ((row & 7) << 4)));
    }
#pragma unroll
    for (int mi = 0; mi < 4; ++mi)
#pragma unroll
      for (int nj = 0; nj < 4; ++nj)
        acc[mi][nj] = __builtin_amdgcn_mfma_f32_16x16x32_bf16(af[mi], bfr[nj], acc[mi][nj], 0, 0, 0);
    __syncthreads();
  }

  const size_t rbase = (size_t)rt * 128;
  const int gbase = gt * 128;
#pragma unroll
  for (int mi = 0; mi < 4; ++mi)
#pragma unroll
    for (int nj = 0; nj < 4; ++nj) {
      int col = gbase + cw + nj * 16 + (lane & 15);
#pragma unroll
      for (int rr = 0; rr < 4; ++rr) {
        int row = rw + mi * 16 + (lane >> 4) * 4 + rr;
        gi[(rbase + row) * 3072 + col] = f2bf(acc[mi][nj][rr]);
      }
    }
}

// ---------------- phase B: persistent GRU scan (agent-scope, proven mechanism) ----------------
// 4 groups x 16 rows; 16 blocks/group x 64 cols x 1024 thr (16 waves).
// Wave w: col-quad cq=w>>2 (16 cols), K-quad kq=w&3 (K=256). W_hh 96 VGPR/lane.
// Sync per step: relaxed agent add + relaxed agent poll (proven round 2).
// h loads = agent-scope relaxed u64 atomics -> NO buffer_inv anywhere.
__launch_bounds__(1024)
__global__ void gru_scan_kernel(const u16* __restrict__ gi, const u16* __restrict__ whh,
                                const float* __restrict__ h0,
                                const float* __restrict__ b_ih, const float* __restrict__ b_hh,
                                u16* __restrict__ hbuf, u32* __restrict__ bar,
                                float* __restrict__ out) {
  const int tid = threadIdx.x, lane = tid & 63, w = tid >> 6;
  const int grp = blockIdx.x >> 4;          // 4 groups of 16 blocks
  const int col0 = (blockIdx.x & 15) * 64;  // this block's 64 gate/hidden cols
  const int cq = w >> 2, kq = w & 3;        // wave: col-quad, K-quad

  __shared__ float part[12 * 64 * 18];      // [(kq*3+g)*64 + col][row], stride 18
  __shared__ int dead_s;
  if (tid == 0) dead_s = 0;

  // W_hh fragments: B-operand (lane&15 = col, (lane>>4)*8 = k) — 24 frags = 96 VGPR
  bf16x8 wreg[3][8];
#pragma unroll
  for (int g = 0; g < 3; ++g) {
    const u16* wp = whh + (size_t)(g * 1024 + col0 + cq * 16 + (lane & 15)) * 1024
                        + kq * 256 + (lane >> 4) * 8;
#pragma unroll
    for (int kk = 0; kk < 8; ++kk) wreg[g][kk] = *(const bf16x8*)(wp + kk * 32);
  }

  // elementwise: (row r = w, col c = lane) — one output per thread, fully coalesced
  const int en = grp * 16 + w;
  const int gcol = col0 + lane;
  const float bihr = b_ih[gcol], bihz = b_ih[1024 + gcol], bihn = b_ih[2048 + gcol];
  const float bhhr = b_hh[gcol], bhhz = b_hh[1024 + gcol], bhhn = b_hh[2048 + gcol];
  float hcur = h0[(size_t)en * 1024 + gcol];

  u32* cnt = bar + grp * 64;                    // per-group counter, 256B apart
  u16* hbase = hbuf + (size_t)grp * 32768;      // [2][16][1024] u16
  const int aoff = (lane & 15) * 1024 + kq * 256 + (lane >> 4) * 8;

  for (int s4 = 0; s4 < 256; ++s4) {
    float ob[4];
#pragma unroll
    for (int u = 0; u < 4; ++u) {
      const int s = s4 * 4 + u;
      const u16* hb  = hbase + (u & 1) * 16384;        // s parity == u parity
      u16*       hbn = hbase + ((u + 1) & 1) * 16384;

      // gi loads (read-only, nontemporal) — issued before the wait, ack during it
      size_t gib = ((size_t)(s * 64 + en)) * 3072 + gcol;
      float gir = bf2f(__builtin_nontemporal_load(gi + gib));
      float giz = bf2f(__builtin_nontemporal_load(gi + gib + 1024));
      float gin = bf2f(__builtin_nontemporal_load(gi + gib + 2048));

      // ---- wait: peers' h(s) stores visible (16 arrivals/group) ----
      if (s > 0) {
        if (tid == 0) {
          const u32 tgt = 16u * (u32)s;
          u32 v = 0, tries = 0;
          do {
            v = __hip_atomic_load(cnt, __ATOMIC_RELAXED, __HIP_MEMORY_SCOPE_AGENT);
          } while (v < tgt && ++tries < (1u << 24));
          if (v < tgt) dead_s = 1;        // bounded-spin escape: fail fast, no hang
        }
        __syncthreads();                  // sync#B (also orders part read/write)
        if (dead_s) break;
      }

      // h fragments: agent-scope relaxed u64 atomic loads (coherent, no inv needed)
      const u16* hp = hb + aoff;
      bf16x8 af[8];
#pragma unroll
      for (int kk = 0; kk < 8; ++kk) {
        union { u64 q[2]; bf16x8 v; } t;
        const u64* qp = (const u64*)(hp + kk * 32);
        t.q[0] = __hip_atomic_load(qp + 0, __ATOMIC_RELAXED, __HIP_MEMORY_SCOPE_AGENT);
        t.q[1] = __hip_atomic_load(qp + 1, __ATOMIC_RELAXED, __HIP_MEMORY_SCOPE_AGENT);
        af[kk] = t.v;
      }

      f32x4 acc[3];
      acc[0] = (f32x4){0.f, 0.f, 0.f, 0.f}; acc[1] = acc[0]; acc[2] = acc[0];
#pragma unroll
      for (int kk = 0; kk < 8; ++kk) {
        acc[0] = __builtin_amdgcn_mfma_f32_16x16x32_bf16(af[kk], wreg[0][kk], acc[0], 0, 0, 0);
        acc[1] = __builtin_amdgcn_mfma_f32_16x16x32_bf16(af[kk], wreg[1][kk], acc[1], 0, 0, 0);
        acc[2] = __builtin_amdgcn_mfma_f32_16x16x32_bf16(af[kk], wreg[2][kk], acc[2], 0, 0, 0);
      }
      // C/D: col = lane&15 (gate col), row = (lane>>4)*4+reg (h row 0..15)
#pragma unroll
      for (int g = 0; g < 3; ++g)
        *(f32x4*)&part[(((kq * 3 + g) * 64) + cq * 16 + (lane & 15)) * 18 + (lane >> 4) * 4]
            = acc[g];
      __syncthreads();                    // sync#C

      // K-split reduction (4 partials) + gates
      float ghr = 0.f, ghz = 0.f, ghn = 0.f;
#pragma unroll
      for (int q = 0; q < 4; ++q) {
        ghr += part[((q * 3 + 0) * 64 + lane) * 18 + w];
        ghz += part[((q * 3 + 1) * 64 + lane) * 18 + w];
        ghn += part[((q * 3 + 2) * 64 + lane) * 18 + w];
      }
      float rg = sigmf(gir + bihr + ghr + bhhr);
      float zg = sigmf(giz + bihz + ghz + bhhz);
      float ng = tanhf_fast(gin + bihn + rg * (ghn + bhhn));
      float hn = (1.f - zg) * ng + zg * hcur;
      hcur = hn;
      ob[u] = hn;

      // h broadcast: packed u32, agent-scope relaxed store (proven write path)
      u32 me = f2bf(hn);
      u32 nb = __shfl_down(me, 1);
      if (!(lane & 1))
        __hip_atomic_store((u32*)&hbn[w * 1024 + gcol], me | (nb << 16),
                           __ATOMIC_RELAXED, __HIP_MEMORY_SCOPE_AGENT);

      __syncthreads();                    // sync#A: drains h stores to coherence pt
      if (tid == 0)
        __hip_atomic_fetch_add(cnt, 1u, __ATOMIC_RELAXED, __HIP_MEMORY_SCOPE_AGENT);
    }
    if (dead_s) break;

    // out flush (4 steps) — issued post-arrive; acks overlap next step's wait
#pragma unroll
    for (int u = 0; u < 4; ++u)
      __builtin_nontemporal_store(ob[u],
          &out[(size_t)en * 1048576 + (size_t)(s4 * 4 + u) * 1024 + gcol]);
  }

  // final hidden state h(1024)
  if (!dead_s)
    out[(size_t)67108864 + (size_t)en * 1024 + gcol] = hcur;
}

// ---------------- launch ----------------
extern "C" void kernel_launch(void* const* d_in, const int* in_sizes, int n_in,
                              void* d_out, int out_size, void* d_ws, size_t ws_size,
                              hipStream_t stream) {
  const float* x     = (const float*)d_in[0];
  const float* h0    = (const float*)d_in[1];
  const float* wih_f = (const float*)d_in[2];
  const float* whh_f = (const float*)d_in[3];
  const float* bih   = (const float*)d_in[4];
  const float* bhh   = (const float*)d_in[5];
  float* out = (float*)d_out;

  if (ws_size < WS_END) return;

  char* ws = (char*)d_ws;
  u32* bar   = (u32*)(ws + WS_BAR);
  u16* hbuf  = (u16*)(ws + WS_HBUF);
  u16* wih_b = (u16*)(ws + WS_WIH);
  u16* whh_b = (u16*)(ws + WS_WHH);
  u16* gi    = (u16*)(ws + WS_GI);

  hipMemsetAsync(bar, 0, 4096, stream);   // counters zeroed every replay

  cvt4_kernel<<<3072, 256, 0, stream>>>(wih_f, wih_b, 786432);
  cvt4_kernel<<<3072, 256, 0, stream>>>(whh_f, whh_b, 786432);
  h0_init_kernel<<<64, 256, 0, stream>>>(h0, hbuf);

  gemm_gi_kernel<<<12288, 256, 0, stream>>>(x, wih_b, gi);

  gru_scan_kernel<<<64, 1024, 0, stream>>>(gi, whh_b, h0, bih, bhh, hbuf, bar, out);
}

// Round 7
// 5740.944 us; speedup vs baseline: 2.4361x; 2.4361x over previous
//
#include <hip/hip_runtime.h>
#include <cstdint>
#include <cstddef>

// ---------------- types / helpers ----------------
typedef __attribute__((ext_vector_type(8))) short bf16x8;   // 8 bf16 in 4 VGPRs
typedef __attribute__((ext_vector_type(4))) float f32x4;
typedef __attribute__((ext_vector_type(4))) float float4v;
typedef __attribute__((ext_vector_type(4))) unsigned short ushort4v;
typedef unsigned short u16;
typedef unsigned int u32;

#define DEVFN static __device__ __forceinline__

DEVFN u16 f2bf(float f) {               // fp32 -> bf16 round-to-nearest-even
  u32 u = __float_as_uint(f);
  return (u16)((u + 0x7fffu + ((u >> 16) & 1u)) >> 16);
}
DEVFN float bf2f(u16 h) { return __uint_as_float(((u32)h) << 16); }
DEVFN float sigmf(float x) { return 1.f / (1.f + __expf(-x)); }
DEVFN float tanhf_fast(float x) {
  float e = __expf(-2.f * fabsf(x));
  float t = (1.f - e) / (1.f + e);
  return x >= 0.f ? t : -t;
}

// dims: L=8 N=64 T=128 D=1024 H=1024 ; TL = 1024 steps ; 3H = 3072
// ws: [0,32768) arrival cells: 4 groups x 64 cells x 128B (one line per block)
//     [32768,+256KB) h bf16 double buffer [2][64][1024]
static constexpr size_t WS_BAR  = 0;
static constexpr size_t WS_HBUF = 32768;
static constexpr size_t WS_WIH  = WS_HBUF + 262144;
static constexpr size_t WS_WHH  = WS_WIH + 6291456;
static constexpr size_t WS_GI   = WS_WHH + 6291456;
static constexpr size_t WS_END  = WS_GI + (size_t)65536 * 3072 * 2;  // ~396 MiB

// ---------------- fp32 -> bf16 convert ----------------
__global__ void cvt4_kernel(const float* __restrict__ src, u16* __restrict__ dst, int n4) {
  int i = blockIdx.x * blockDim.x + threadIdx.x;
  if (i >= n4) return;
  float4v v = ((const float4v*)src)[i];
  ushort4v o;
  o[0] = f2bf(v[0]); o[1] = f2bf(v[1]); o[2] = f2bf(v[2]); o[3] = f2bf(v[3]);
  ((ushort4v*)dst)[i] = o;
}

// ---------------- phase A: gi = xs @ W_ih^T (bf16 out) — unchanged, proven ----------------
__launch_bounds__(256, 2)
__global__ void gemm_gi_kernel(const float* __restrict__ x, const u16* __restrict__ wih,
                               u16* __restrict__ gi) {
  const int tid = threadIdx.x;
  const int lane = tid & 63;
  const int wv = tid >> 6;
  const int bid = blockIdx.x;
  const int gt = bid % 24;
  const int rt = bid / 24;

  __shared__ __align__(16) u16 Ash[128 * 32];
  __shared__ __align__(16) u16 Bsh[128 * 32];

  const int ra = tid >> 1;
  const int ch = (tid & 1) * 16;
  const int r  = rt * 128 + ra;
  const int tp = r >> 6, n = r & 63;
  const int ll = tp & 7, tt = tp >> 3;
  const float* arow = x + ((size_t)((ll * 64 + n) * 128 + tt)) * 1024 + ch;
  const u16*   brow = wih + ((size_t)(gt * 128 + ra)) * 1024 + ch;
  const int wbyte0 = ra * 64 + ch * 2;
  const int wswz   = (ra & 7) << 4;

  const int rw = (wv >> 1) * 64;
  const int cw = (wv & 1) * 64;
  const int kb = (lane >> 4) * 16;

  f32x4 acc[4][4];
#pragma unroll
  for (int i = 0; i < 4; ++i)
#pragma unroll
    for (int j = 0; j < 4; ++j) acc[i][j] = (f32x4){0.f, 0.f, 0.f, 0.f};

  for (int kt = 0; kt < 32; ++kt) {
    float4v a0 = *(const float4v*)(arow + kt * 32 + 0);
    float4v a1 = *(const float4v*)(arow + kt * 32 + 4);
    float4v a2 = *(const float4v*)(arow + kt * 32 + 8);
    float4v a3 = *(const float4v*)(arow + kt * 32 + 12);
    bf16x8 b0 = *(const bf16x8*)(brow + kt * 32 + 0);
    bf16x8 b1 = *(const bf16x8*)(brow + kt * 32 + 8);
    union { u16 u[8]; bf16x8 v; } p0, p1;
    p0.u[0] = f2bf(a0[0]); p0.u[1] = f2bf(a0[1]); p0.u[2] = f2bf(a0[2]); p0.u[3] = f2bf(a0[3]);
    p0.u[4] = f2bf(a1[0]); p0.u[5] = f2bf(a1[1]); p0.u[6] = f2bf(a1[2]); p0.u[7] = f2bf(a1[3]);
    p1.u[0] = f2bf(a2[0]); p1.u[1] = f2bf(a2[1]); p1.u[2] = f2bf(a2[2]); p1.u[3] = f2bf(a2[3]);
    p1.u[4] = f2bf(a3[0]); p1.u[5] = f2bf(a3[1]); p1.u[6] = f2bf(a3[2]); p1.u[7] = f2bf(a3[3]);
    *(bf16x8*)((char*)Ash + ((wbyte0 +  0) ^ wswz)) = p0.v;
    *(bf16x8*)((char*)Ash + ((wbyte0 + 16) ^ wswz)) = p1.v;
    *(bf16x8*)((char*)Bsh + ((wbyte0 +  0) ^ wswz)) = b0;
    *(bf16x8*)((char*)Bsh + ((wbyte0 + 16) ^ wswz)) = b1;
    __syncthreads();

    bf16x8 af[4], bfr[4];
#pragma unroll
    for (int mi = 0; mi < 4; ++mi) {
      int row = rw + mi * 16 + (lane & 15);
      af[mi] = *(const bf16x8*)((char*)Ash + ((row * 64 + kb) ^ ((row & 7) << 4)));
    }
#pragma unroll
    for (int nj = 0; nj < 4; ++nj) {
      int row = cw + nj * 16 + (lane & 15);
      bfr[nj] = *(const bf16x8*)((char*)Bsh + ((row * 64 + kb) ^ ((row & 7) << 4)));
    }
#pragma unroll
    for (int mi = 0; mi < 4; ++mi)
#pragma unroll
      for (int nj = 0; nj < 4; ++nj)
        acc[mi][nj] = __builtin_amdgcn_mfma_f32_16x16x32_bf16(af[mi], bfr[nj], acc[mi][nj], 0, 0, 0);
    __syncthreads();
  }

  const size_t rbase = (size_t)rt * 128;
  const int gbase = gt * 128;
#pragma unroll
  for (int mi = 0; mi < 4; ++mi)
#pragma unroll
    for (int nj = 0; nj < 4; ++nj) {
      int col = gbase + cw + nj * 16 + (lane & 15);
#pragma unroll
      for (int rr = 0; rr < 4; ++rr) {
        int row = rw + mi * 16 + (lane >> 4) * 4 + rr;
        gi[(rbase + row) * 3072 + col] = f2bf(acc[mi][nj][rr]);
      }
    }
}

// ---------------- phase B: persistent GRU scan ----------------
// Round-2 proven structure. ONLY change: arrive = fetch_add on a PER-BLOCK cell
// (128B-strided -> parallel RMWs, no same-address serialization); wait = wave 0
// polls all 64 cells, one lane each. Everything else identical to round 2:
// relaxed agent h stores, one acquire fence (buffer_inv) per step, plain 16B
// h loads, stride-17 part buffer.
__launch_bounds__(256, 2)
__global__ void gru_scan_kernel(const u16* __restrict__ gi, const u16* __restrict__ whh,
                                const float* __restrict__ h0,
                                const float* __restrict__ b_ih, const float* __restrict__ b_hh,
                                u16* __restrict__ hbuf, u32* __restrict__ bar,
                                float* __restrict__ out) {
  const int tid = threadIdx.x, lane = tid & 63, wv = tid >> 6;
  const int b = blockIdx.x;
  const int grp = b >> 6;          // batch rows grp*16 .. +16
  const int j0 = (b & 63) * 16;    // hidden cols j0 .. j0+16

  __shared__ float part[4 * 3 * 16 * 17];   // [wave][gate][col][row], stride 17
  __shared__ int dead_s;
  if (tid == 0) dead_s = 0;
  __syncthreads();

  // W_hh fragments: wave wv owns K in [wv*256, +256)
  bf16x8 wreg[3][8];
#pragma unroll
  for (int c = 0; c < 3; ++c) {
    const u16* wp = whh + (size_t)(c * 1024 + j0 + (lane & 15)) * 1024
                        + wv * 256 + (lane >> 4) * 8;
#pragma unroll
    for (int kk = 0; kk < 8; ++kk) wreg[c][kk] = *(const bf16x8*)(wp + kk * 32);
  }

  const int erow = tid >> 4, ej = tid & 15;
  const int en = grp * 16 + erow;
  const int gcol = j0 + ej;
  const float bihr = b_ih[gcol], bihz = b_ih[1024 + gcol], bihn = b_ih[2048 + gcol];
  const float bhhr = b_hh[gcol], bhhz = b_hh[1024 + gcol], bhhn = b_hh[2048 + gcol];
  float hcur = h0[(size_t)en * 1024 + gcol];

  u32* cells  = bar + grp * 2048;           // group stride 8KB; cell stride 128B
  u32* mycell = cells + (b & 63) * 32;
  const int aoff = (grp * 16 + (lane & 15)) * 1024 + wv * 256 + (lane >> 4) * 8;

  for (int s = 0; s < 1024; ++s) {
    const u16* hb  = hbuf + (size_t)(s & 1) * 65536;
    u16*       hbn = hbuf + (size_t)((s + 1) & 1) * 65536;

    // gi loads (read-once, streaming) — independent of h
    size_t gib = ((size_t)(s * 64 + en)) * 3072 + gcol;
    float gir = bf2f(__builtin_nontemporal_load(gi + gib));
    float giz = bf2f(__builtin_nontemporal_load(gi + gib + 1024));
    float gin = bf2f(__builtin_nontemporal_load(gi + gib + 2048));

    // h fragments: plain 16B loads (fresh: L1+L2 invalidated by last step's fence)
    const u16* hp = hb + aoff;
    bf16x8 af[8];
#pragma unroll
    for (int kk = 0; kk < 8; ++kk) af[kk] = *(const bf16x8*)(hp + kk * 32);

    f32x4 acc[3];
    acc[0] = (f32x4){0.f, 0.f, 0.f, 0.f}; acc[1] = acc[0]; acc[2] = acc[0];
#pragma unroll
    for (int kk = 0; kk < 8; ++kk) {
      acc[0] = __builtin_amdgcn_mfma_f32_16x16x32_bf16(af[kk], wreg[0][kk], acc[0], 0, 0, 0);
      acc[1] = __builtin_amdgcn_mfma_f32_16x16x32_bf16(af[kk], wreg[1][kk], acc[1], 0, 0, 0);
      acc[2] = __builtin_amdgcn_mfma_f32_16x16x32_bf16(af[kk], wreg[2][kk], acc[2], 0, 0, 0);
    }
#pragma unroll
    for (int c = 0; c < 3; ++c) {
      float* pp = &part[((wv * 3 + c) * 16 + (lane & 15)) * 17 + (lane >> 4) * 4];
      pp[0] = acc[c][0]; pp[1] = acc[c][1]; pp[2] = acc[c][2]; pp[3] = acc[c][3];
    }
    __syncthreads();

    float ghr = 0.f, ghz = 0.f, ghn = 0.f;
#pragma unroll
    for (int ww = 0; ww < 4; ++ww) {
      ghr += part[((ww * 3 + 0) * 16 + ej) * 17 + erow];
      ghz += part[((ww * 3 + 1) * 16 + ej) * 17 + erow];
      ghn += part[((ww * 3 + 2) * 16 + ej) * 17 + erow];
    }
    float rg = sigmf(gir + bihr + ghr + bhhr);
    float zg = sigmf(giz + bihz + ghz + bhhz);
    float ng = tanhf_fast(gin + bihn + rg * (ghn + bhhn));
    float hn = (1.f - zg) * ng + zg * hcur;
    hcur = hn;

    // h broadcast: packed u32, agent-scope relaxed store (proven write path)
    u32 me = f2bf(hn);
    u32 nb = __shfl_down(me, 1);
    if (!(ej & 1))
      __hip_atomic_store((u32*)&hbn[en * 1024 + gcol], me | (nb << 16),
                         __ATOMIC_RELAXED, __HIP_MEMORY_SCOPE_AGENT);

    // ---- group barrier: parallel per-cell RMW arrive + wave-parallel poll ----
    __syncthreads();                 // drains h stores (vmcnt0) -> L3-visible
    if (tid == 0)
      __hip_atomic_fetch_add(mycell, 1u, __ATOMIC_RELAXED, __HIP_MEMORY_SCOPE_AGENT);
    if (wv == 0) {
      const u32 tgt = (u32)(s + 1);
      u32 tries = 0; int ok;
      do {
        u32 v = __hip_atomic_load(cells + lane * 32, __ATOMIC_RELAXED, __HIP_MEMORY_SCOPE_AGENT);
        ok = __all((int)(v >= tgt));
      } while (!ok && ++tries < (1u << 20));
      if (!ok && lane == 0) dead_s = 1;        // bounded-spin escape: fail fast
      __builtin_amdgcn_fence(__ATOMIC_ACQUIRE, "agent");  // one buffer_inv (+L1 inv)
    }
    __syncthreads();
    if (dead_s) break;

    // out stores post-barrier: HBM acks overlap next step's work
    __builtin_nontemporal_store(hn, &out[(size_t)en * 1048576 + (size_t)s * 1024 + gcol]);
    if (s == 1023) out[(size_t)67108864 + (size_t)en * 1024 + gcol] = hn;
  }
}

// ---------------- launch ----------------
extern "C" void kernel_launch(void* const* d_in, const int* in_sizes, int n_in,
                              void* d_out, int out_size, void* d_ws, size_t ws_size,
                              hipStream_t stream) {
  const float* x     = (const float*)d_in[0];
  const float* h0    = (const float*)d_in[1];
  const float* wih_f = (const float*)d_in[2];
  const float* whh_f = (const float*)d_in[3];
  const float* bih   = (const float*)d_in[4];
  const float* bhh   = (const float*)d_in[5];
  float* out = (float*)d_out;

  if (ws_size < WS_END) return;

  char* ws = (char*)d_ws;
  u32* bar   = (u32*)(ws + WS_BAR);
  u16* hbuf  = (u16*)(ws + WS_HBUF);
  u16* wih_b = (u16*)(ws + WS_WIH);
  u16* whh_b = (u16*)(ws + WS_WHH);
  u16* gi    = (u16*)(ws + WS_GI);

  hipMemsetAsync(bar, 0, 32768, stream);  // all arrival cells zeroed every replay

  cvt4_kernel<<<3072, 256, 0, stream>>>(wih_f, wih_b, 786432);
  cvt4_kernel<<<3072, 256, 0, stream>>>(whh_f, whh_b, 786432);
  cvt4_kernel<<<64,   256, 0, stream>>>(h0, hbuf, 16384);   // h buffer 0 init

  gemm_gi_kernel<<<12288, 256, 0, stream>>>(x, wih_b, gi);

  gru_scan_kernel<<<256, 256, 0, stream>>>(gi, whh_b, h0, bih, bhh, hbuf, bar, out);
}

// Round 9
// 4572.538 us; speedup vs baseline: 3.0586x; 1.2555x over previous
//
#include <hip/hip_runtime.h>
#include <cstdint>
#include <cstddef>

// ---------------- types / helpers ----------------
typedef __attribute__((ext_vector_type(8))) short bf16x8;   // 8 bf16 in 4 VGPRs
typedef __attribute__((ext_vector_type(4))) float f32x4;
typedef __attribute__((ext_vector_type(4))) float float4v;
typedef __attribute__((ext_vector_type(4))) unsigned short ushort4v;
typedef unsigned short u16;
typedef unsigned int u32;

#define DEVFN static __device__ __forceinline__

DEVFN u16 f2bf(float f) {               // fp32 -> bf16 round-to-nearest-even
  u32 u = __float_as_uint(f);
  return (u16)((u + 0x7fffu + ((u >> 16) & 1u)) >> 16);
}
DEVFN float bf2f(u16 h) { return __uint_as_float(((u32)h) << 16); }
DEVFN float sigmf(float x) { return 1.f / (1.f + __expf(-x)); }
DEVFN float tanhf_fast(float x) {
  float e = __expf(-2.f * fabsf(x));
  float t = (1.f - e) / (1.f + e);
  return x >= 0.f ? t : -t;
}

// dims: L=8 N=64 T=128 D=1024 H=1024 ; TL = 1024 steps ; 3H = 3072
// ws: [0,32768) arrival cells: 4 groups x 64 cells x 128B (one line per block)
//     [32768,+256KB) h bf16 double buffer [2][64][1024]
static constexpr size_t WS_BAR  = 0;
static constexpr size_t WS_HBUF = 32768;
static constexpr size_t WS_WIH  = WS_HBUF + 262144;
static constexpr size_t WS_WHH  = WS_WIH + 6291456;
static constexpr size_t WS_GI   = WS_WHH + 6291456;
static constexpr size_t WS_END  = WS_GI + (size_t)65536 * 3072 * 2;  // ~396 MiB

// ---------------- fp32 -> bf16 convert ----------------
__global__ void cvt4_kernel(const float* __restrict__ src, u16* __restrict__ dst, int n4) {
  int i = blockIdx.x * blockDim.x + threadIdx.x;
  if (i >= n4) return;
  float4v v = ((const float4v*)src)[i];
  ushort4v o;
  o[0] = f2bf(v[0]); o[1] = f2bf(v[1]); o[2] = f2bf(v[2]); o[3] = f2bf(v[3]);
  ((ushort4v*)dst)[i] = o;
}

// ---------------- phase A: gi = xs @ W_ih^T (bf16 out) — unchanged, proven ----------------
__launch_bounds__(256, 2)
__global__ void gemm_gi_kernel(const float* __restrict__ x, const u16* __restrict__ wih,
                               u16* __restrict__ gi) {
  const int tid = threadIdx.x;
  const int lane = tid & 63;
  const int wv = tid >> 6;
  const int bid = blockIdx.x;
  const int gt = bid % 24;
  const int rt = bid / 24;

  __shared__ __align__(16) u16 Ash[128 * 32];
  __shared__ __align__(16) u16 Bsh[128 * 32];

  const int ra = tid >> 1;
  const int ch = (tid & 1) * 16;
  const int r  = rt * 128 + ra;
  const int tp = r >> 6, n = r & 63;
  const int ll = tp & 7, tt = tp >> 3;
  const float* arow = x + ((size_t)((ll * 64 + n) * 128 + tt)) * 1024 + ch;
  const u16*   brow = wih + ((size_t)(gt * 128 + ra)) * 1024 + ch;
  const int wbyte0 = ra * 64 + ch * 2;
  const int wswz   = (ra & 7) << 4;

  const int rw = (wv >> 1) * 64;
  const int cw = (wv & 1) * 64;
  const int kb = (lane >> 4) * 16;

  f32x4 acc[4][4];
#pragma unroll
  for (int i = 0; i < 4; ++i)
#pragma unroll
    for (int j = 0; j < 4; ++j) acc[i][j] = (f32x4){0.f, 0.f, 0.f, 0.f};

  for (int kt = 0; kt < 32; ++kt) {
    float4v a0 = *(const float4v*)(arow + kt * 32 + 0);
    float4v a1 = *(const float4v*)(arow + kt * 32 + 4);
    float4v a2 = *(const float4v*)(arow + kt * 32 + 8);
    float4v a3 = *(const float4v*)(arow + kt * 32 + 12);
    bf16x8 b0 = *(const bf16x8*)(brow + kt * 32 + 0);
    bf16x8 b1 = *(const bf16x8*)(brow + kt * 32 + 8);
    union { u16 u[8]; bf16x8 v; } p0, p1;
    p0.u[0] = f2bf(a0[0]); p0.u[1] = f2bf(a0[1]); p0.u[2] = f2bf(a0[2]); p0.u[3] = f2bf(a0[3]);
    p0.u[4] = f2bf(a1[0]); p0.u[5] = f2bf(a1[1]); p0.u[6] = f2bf(a1[2]); p0.u[7] = f2bf(a1[3]);
    p1.u[0] = f2bf(a2[0]); p1.u[1] = f2bf(a2[1]); p1.u[2] = f2bf(a2[2]); p1.u[3] = f2bf(a2[3]);
    p1.u[4] = f2bf(a3[0]); p1.u[5] = f2bf(a3[1]); p1.u[6] = f2bf(a3[2]); p1.u[7] = f2bf(a3[3]);
    *(bf16x8*)((char*)Ash + ((wbyte0 +  0) ^ wswz)) = p0.v;
    *(bf16x8*)((char*)Ash + ((wbyte0 + 16) ^ wswz)) = p1.v;
    *(bf16x8*)((char*)Bsh + ((wbyte0 +  0) ^ wswz)) = b0;
    *(bf16x8*)((char*)Bsh + ((wbyte0 + 16) ^ wswz)) = b1;
    __syncthreads();

    bf16x8 af[4], bfr[4];
#pragma unroll
    for (int mi = 0; mi < 4; ++mi) {
      int row = rw + mi * 16 + (lane & 15);
      af[mi] = *(const bf16x8*)((char*)Ash + ((row * 64 + kb) ^ ((row & 7) << 4)));
    }
#pragma unroll
    for (int nj = 0; nj < 4; ++nj) {
      int row = cw + nj * 16 + (lane & 15);
      bfr[nj] = *(const bf16x8*)((char*)Bsh + ((row * 64 + kb) ^ ((row & 7) << 4)));
    }
#pragma unroll
    for (int mi = 0; mi < 4; ++mi)
#pragma unroll
      for (int nj = 0; nj < 4; ++nj)
        acc[mi][nj] = __builtin_amdgcn_mfma_f32_16x16x32_bf16(af[mi], bfr[nj], acc[mi][nj], 0, 0, 0);
    __syncthreads();
  }

  const size_t rbase = (size_t)rt * 128;
  const int gbase = gt * 128;
#pragma unroll
  for (int mi = 0; mi < 4; ++mi)
#pragma unroll
    for (int nj = 0; nj < 4; ++nj) {
      int col = gbase + cw + nj * 16 + (lane & 15);
#pragma unroll
      for (int rr = 0; rr < 4; ++rr) {
        int row = rw + mi * 16 + (lane >> 4) * 4 + rr;
        gi[(rbase + row) * 3072 + col] = f2bf(acc[mi][nj][rr]);
      }
    }
}

// ---------------- phase B: persistent GRU scan ----------------
// r7 structure (passed) with r5's proven FENCE-FREE semantics:
//   arrive = per-block-cell RMW (r7-proven), poll = agent atomic loads (r5/r7),
//   h stores = agent relaxed atomic (r2/r5/r7), h loads = sc0+sc1 16B (L3-direct,
//   the 16B form of r5's proven 8B atomic loads). NO per-step fence ->
//   L2 keeps gi warm across steps (expect FETCH_SIZE to drop ~1GB).
__launch_bounds__(256, 2)
__global__ void gru_scan_kernel(const u16* __restrict__ gi, const u16* __restrict__ whh,
                                const float* __restrict__ h0,
                                const float* __restrict__ b_ih, const float* __restrict__ b_hh,
                                u16* __restrict__ hbuf, u32* __restrict__ bar,
                                float* __restrict__ out) {
  const int tid = threadIdx.x, lane = tid & 63, wv = tid >> 6;
  const int b = blockIdx.x;
  const int grp = b >> 6;          // batch rows grp*16 .. +16
  const int j0 = (b & 63) * 16;    // hidden cols j0 .. j0+16

  __shared__ float part[4 * 3 * 16 * 17];   // [wave][gate][col][row], stride 17
  __shared__ int dead_s;
  if (tid == 0) dead_s = 0;
  __syncthreads();

  // W_hh fragments: wave wv owns K in [wv*256, +256)
  bf16x8 wreg[3][8];
#pragma unroll
  for (int c = 0; c < 3; ++c) {
    const u16* wp = whh + (size_t)(c * 1024 + j0 + (lane & 15)) * 1024
                        + wv * 256 + (lane >> 4) * 8;
#pragma unroll
    for (int kk = 0; kk < 8; ++kk) wreg[c][kk] = *(const bf16x8*)(wp + kk * 32);
  }

  const int erow = tid >> 4, ej = tid & 15;
  const int en = grp * 16 + erow;
  const int gcol = j0 + ej;
  const float bihr = b_ih[gcol], bihz = b_ih[1024 + gcol], bihn = b_ih[2048 + gcol];
  const float bhhr = b_hh[gcol], bhhz = b_hh[1024 + gcol], bhhn = b_hh[2048 + gcol];
  float hcur = h0[(size_t)en * 1024 + gcol];

  u32* cells  = bar + grp * 2048;           // group stride 8KB; cell stride 128B
  u32* mycell = cells + (b & 63) * 32;
  const int aoff = (grp * 16 + (lane & 15)) * 1024 + wv * 256 + (lane >> 4) * 8;

  for (int s = 0; s < 1024; ++s) {
    const u16* hb  = hbuf + (size_t)(s & 1) * 65536;
    u16*       hbn = hbuf + (size_t)((s + 1) & 1) * 65536;

    // gi loads (read-once, streaming) — L2 stays warm now (no per-step inv)
    size_t gib = ((size_t)(s * 64 + en)) * 3072 + gcol;
    float gir = bf2f(__builtin_nontemporal_load(gi + gib));
    float giz = bf2f(__builtin_nontemporal_load(gi + gib + 1024));
    float gin = bf2f(__builtin_nontemporal_load(gi + gib + 2048));

    // h fragments: sc0+sc1 16B loads — bypass L1+L2, read L3 directly.
    // Fresh by: producers' sc-stores vmcnt-drained before their arrive-RMW at L3,
    // and our previous-iteration poll observed all arrive cells (r5-proven logic).
    const u16* hp = hb + aoff;
    bf16x8 af0, af1, af2, af3, af4, af5, af6, af7;
    asm volatile("global_load_dwordx4 %0, %1, off sc0 sc1"            : "=v"(af0) : "v"(hp));
    asm volatile("global_load_dwordx4 %0, %1, off offset:64 sc0 sc1"  : "=v"(af1) : "v"(hp));
    asm volatile("global_load_dwordx4 %0, %1, off offset:128 sc0 sc1" : "=v"(af2) : "v"(hp));
    asm volatile("global_load_dwordx4 %0, %1, off offset:192 sc0 sc1" : "=v"(af3) : "v"(hp));
    asm volatile("global_load_dwordx4 %0, %1, off offset:256 sc0 sc1" : "=v"(af4) : "v"(hp));
    asm volatile("global_load_dwordx4 %0, %1, off offset:320 sc0 sc1" : "=v"(af5) : "v"(hp));
    asm volatile("global_load_dwordx4 %0, %1, off offset:384 sc0 sc1" : "=v"(af6) : "v"(hp));
    asm volatile("global_load_dwordx4 %0, %1, off offset:448 sc0 sc1" : "=v"(af7) : "v"(hp));
    asm volatile("s_waitcnt vmcnt(0)" ::: "memory");
    __builtin_amdgcn_sched_barrier(0);      // rule #18: keep MFMA below the waitcnt

    f32x4 acc[3];
    acc[0] = (f32x4){0.f, 0.f, 0.f, 0.f}; acc[1] = acc[0]; acc[2] = acc[0];
#pragma unroll
    for (int c = 0; c < 3; ++c) {
      acc[c] = __builtin_amdgcn_mfma_f32_16x16x32_bf16(af0, wreg[c][0], acc[c], 0, 0, 0);
      acc[c] = __builtin_amdgcn_mfma_f32_16x16x32_bf16(af1, wreg[c][1], acc[c], 0, 0, 0);
      acc[c] = __builtin_amdgcn_mfma_f32_16x16x32_bf16(af2, wreg[c][2], acc[c], 0, 0, 0);
      acc[c] = __builtin_amdgcn_mfma_f32_16x16x32_bf16(af3, wreg[c][3], acc[c], 0, 0, 0);
      acc[c] = __builtin_amdgcn_mfma_f32_16x16x32_bf16(af4, wreg[c][4], acc[c], 0, 0, 0);
      acc[c] = __builtin_amdgcn_mfma_f32_16x16x32_bf16(af5, wreg[c][5], acc[c], 0, 0, 0);
      acc[c] = __builtin_amdgcn_mfma_f32_16x16x32_bf16(af6, wreg[c][6], acc[c], 0, 0, 0);
      acc[c] = __builtin_amdgcn_mfma_f32_16x16x32_bf16(af7, wreg[c][7], acc[c], 0, 0, 0);
    }
#pragma unroll
    for (int c = 0; c < 3; ++c) {
      float* pp = &part[((wv * 3 + c) * 16 + (lane & 15)) * 17 + (lane >> 4) * 4];
      pp[0] = acc[c][0]; pp[1] = acc[c][1]; pp[2] = acc[c][2]; pp[3] = acc[c][3];
    }
    __syncthreads();

    float ghr = 0.f, ghz = 0.f, ghn = 0.f;
#pragma unroll
    for (int ww = 0; ww < 4; ++ww) {
      ghr += part[((ww * 3 + 0) * 16 + ej) * 17 + erow];
      ghz += part[((ww * 3 + 1) * 16 + ej) * 17 + erow];
      ghn += part[((ww * 3 + 2) * 16 + ej) * 17 + erow];
    }
    float rg = sigmf(gir + bihr + ghr + bhhr);
    float zg = sigmf(giz + bihz + ghz + bhhz);
    float ng = tanhf_fast(gin + bihn + rg * (ghn + bhhn));
    float hn = (1.f - zg) * ng + zg * hcur;
    hcur = hn;

    // h broadcast: packed u32, agent-scope relaxed store (r2/r5/r7-proven)
    u32 me = f2bf(hn);
    u32 nb = __shfl_down(me, 1);
    if (!(ej & 1))
      __hip_atomic_store((u32*)&hbn[en * 1024 + gcol], me | (nb << 16),
                         __ATOMIC_RELAXED, __HIP_MEMORY_SCOPE_AGENT);

    // ---- group barrier: per-cell RMW arrive + wave-parallel poll (NO fence) ----
    __syncthreads();                 // drains h stores (vmcnt0) -> L3-visible
    if (tid == 0)
      __hip_atomic_fetch_add(mycell, 1u, __ATOMIC_RELAXED, __HIP_MEMORY_SCOPE_AGENT);
    if (wv == 0) {
      const u32 tgt = (u32)(s + 1);
      u32 tries = 0; int ok;
      do {
        u32 v = __hip_atomic_load(cells + lane * 32, __ATOMIC_RELAXED, __HIP_MEMORY_SCOPE_AGENT);
        ok = __all((int)(v >= tgt));
      } while (!ok && ++tries < (1u << 20));
      if (!ok && lane == 0) dead_s = 1;        // bounded-spin escape: fail fast
    }
    __syncthreads();
    if (dead_s) break;

    // out stores post-barrier: HBM acks overlap next step's work
    __builtin_nontemporal_store(hn, &out[(size_t)en * 1048576 + (size_t)s * 1024 + gcol]);
    if (s == 1023) out[(size_t)67108864 + (size_t)en * 1024 + gcol] = hn;
  }
}

// ---------------- launch ----------------
extern "C" void kernel_launch(void* const* d_in, const int* in_sizes, int n_in,
                              void* d_out, int out_size, void* d_ws, size_t ws_size,
                              hipStream_t stream) {
  const float* x     = (const float*)d_in[0];
  const float* h0    = (const float*)d_in[1];
  const float* wih_f = (const float*)d_in[2];
  const float* whh_f = (const float*)d_in[3];
  const float* bih   = (const float*)d_in[4];
  const float* bhh   = (const float*)d_in[5];
  float* out = (float*)d_out;

  if (ws_size < WS_END) return;

  char* ws = (char*)d_ws;
  u32* bar   = (u32*)(ws + WS_BAR);
  u16* hbuf  = (u16*)(ws + WS_HBUF);
  u16* wih_b = (u16*)(ws + WS_WIH);
  u16* whh_b = (u16*)(ws + WS_WHH);
  u16* gi    = (u16*)(ws + WS_GI);

  hipMemsetAsync(bar, 0, 32768, stream);  // all arrival cells zeroed every replay

  cvt4_kernel<<<3072, 256, 0, stream>>>(wih_f, wih_b, 786432);
  cvt4_kernel<<<3072, 256, 0, stream>>>(whh_f, whh_b, 786432);
  cvt4_kernel<<<64,   256, 0, stream>>>(h0, hbuf, 16384);   // h buffer 0 init

  gemm_gi_kernel<<<12288, 256, 0, stream>>>(x, wih_b, gi);

  gru_scan_kernel<<<256, 256, 0, stream>>>(gi, whh_b, h0, bih, bhh, hbuf, bar, out);
}